// Round 2
// baseline (349.059 us; speedup 1.0000x reference)
//
#include <hip/hip_runtime.h>
#include <math.h>

#define HIDDEN 64
#define N_LAYERS 4
#define N_CLASSES 10
#define N_GRAPHS 512
#define BSH 8                        // coarse bucket: 256 nodes
#define NPB 256                      // nodes per bucket
#define PART_K 2048                  // edges per partition block
#define IDX_CAP 512                  // staged csr indices per 16-row tile

typedef _Float16 __h;
typedef __attribute__((ext_vector_type(4))) _Float16 half4;   // 8 B
typedef __attribute__((ext_vector_type(8))) _Float16 half8;   // 16 B, MFMA A/B frag
typedef __attribute__((ext_vector_type(4))) float f32x4;      // MFMA acc

// ---------------- pass 1: global bucket histogram ----------------
__global__ __launch_bounds__(256) void k_histA(const int* __restrict__ dst,
                                               int* __restrict__ ghist, int E, int NB) {
    __shared__ int hist[512];
    int t = threadIdx.x;
    hist[t] = 0; hist[t + 256] = 0;
    __syncthreads();
    int base = blockIdx.x * PART_K;
    int kend = min(PART_K, E - base);
    for (int k = t; k < kend; k += 256) atomicAdd(&hist[dst[base + k] >> BSH], 1);
    __syncthreads();
    for (int j = t; j < NB; j += 256) {
        int h = hist[j];
        if (h) atomicAdd(&ghist[j], h);
    }
}

// ---------------- pass 2: scan bucket sizes -> bases, init cursors ----------------
__global__ __launch_bounds__(256) void k_bucketscan(const int* __restrict__ ghist,
                                                    int* __restrict__ bucketbase,
                                                    int* __restrict__ gcur, int NB) {
    __shared__ int s[256];
    int t = threadIdx.x;
    int j0 = 2 * t, j1 = 2 * t + 1;
    int h0 = (j0 < NB) ? ghist[j0] : 0;
    int h1 = (j1 < NB) ? ghist[j1] : 0;
    s[t] = h0 + h1; __syncthreads();
    for (int o = 1; o < 256; o <<= 1) {
        int x = (t >= o) ? s[t - o] : 0;
        __syncthreads();
        s[t] += x;
        __syncthreads();
    }
    int base = (t == 0) ? 0 : s[t - 1];
    if (j0 <= NB) { bucketbase[j0] = base;      gcur[j0] = base; }
    if (j1 <= NB) { bucketbase[j1] = base + h0; gcur[j1] = base + h0; }
}

// ---------------- pass 3: partition edges into bucket segments (LDS reorder) ----------------
__global__ __launch_bounds__(256) void k_partition(const int* __restrict__ src,
                                                   const int* __restrict__ dst,
                                                   int* __restrict__ gcur,
                                                   int* __restrict__ packed,
                                                   int E, int NB) {
    __shared__ int hist[512];
    __shared__ int scanE[512];
    __shared__ int cur[512];
    __shared__ int delta[512];
    __shared__ int ps[256];
    __shared__ int stage[PART_K];
    __shared__ unsigned short stgj[PART_K];
    int t = threadIdx.x;
    int base = blockIdx.x * PART_K;
    int kend = min(PART_K, E - base);

    hist[t] = 0; hist[t + 256] = 0;
    __syncthreads();
    for (int k = t; k < kend; k += 256) atomicAdd(&hist[dst[base + k] >> BSH], 1);
    __syncthreads();

    int j0 = 2 * t, j1 = j0 + 1;
    int h0 = hist[j0], h1 = hist[j1];
    ps[t] = h0 + h1; __syncthreads();
    for (int o = 1; o < 256; o <<= 1) {
        int x = (t >= o) ? ps[t - o] : 0;
        __syncthreads();
        ps[t] += x;
        __syncthreads();
    }
    int bexc = (t == 0) ? 0 : ps[t - 1];
    scanE[j0] = bexc;
    scanE[j1] = bexc + h0;
    __syncthreads();

    for (int j = t; j < NB; j += 256) {
        int h = hist[j];
        int g = h ? atomicAdd(&gcur[j], h) : 0;
        delta[j] = g - scanE[j];
        cur[j]   = scanE[j];
    }
    __syncthreads();

    for (int k = t; k < kend; k += 256) {
        int d = dst[base + k], s = src[base + k];
        int j = d >> BSH;
        int pos = atomicAdd(&cur[j], 1);
        stage[pos] = (s << BSH) | (d & (NPB - 1));
        stgj[pos]  = (unsigned short)j;
    }
    __syncthreads();

    for (int i = t; i < kend; i += 256) {
        packed[i + delta[stgj[i]]] = stage[i];
    }
}

// ---------------- pass 4: per-bucket CSR fill with SELF-EDGE prepend ----------------
__global__ __launch_bounds__(256) void k_fill3(const int* __restrict__ packed,
                                               const int* __restrict__ bucketbase,
                                               int* __restrict__ rowptr,
                                               float* __restrict__ dis,
                                               int* __restrict__ csr_src,
                                               int N, int E) {
    __shared__ int cnt[256];
    __shared__ int rp[256];
    int j = blockIdx.x;
    int t = threadIdx.x;
    int node0 = j << BSH;
    int segb = bucketbase[j];       // packed (real-edge) base
    int sege = bucketbase[j + 1];

    cnt[t] = 0; __syncthreads();
    for (int i = segb + t; i < sege; i += 256) atomicAdd(&cnt[packed[i] & (NPB - 1)], 1);
    __syncthreads();

    int c = cnt[t];
    rp[t] = c; __syncthreads();
    for (int o = 1; o < 256; o <<= 1) {
        int x = (t >= o) ? rp[t - o] : 0;
        __syncthreads();
        rp[t] += x;
        __syncthreads();
    }
    int node = node0 + t;
    int start = segb + rp[t] - c + node;   // + node = selves before this node
    if (node < N) {
        rowptr[node] = start;
        dis[node] = rsqrtf((float)c + 1.0f);
        csr_src[start] = node;             // self edge first
        if (node == N - 1) rowptr[N] = E + N;
    }
    __syncthreads();
    cnt[t] = start + 1;                    // cursor after the self slot
    __syncthreads();
    for (int i = segb + t; i < sege; i += 256) {
        int v = packed[i];
        int slot = atomicAdd(&cnt[v & (NPB - 1)], 1);
        csr_src[slot] = v >> BSH;
    }
}

// ---------------- fp16 helpers ----------------
__device__ __forceinline__ half4 shfl_xor_h4(half4 v, int m) {
    uint2 u = __builtin_bit_cast(uint2, v);
    u.x = __shfl_xor((int)u.x, m);
    u.y = __shfl_xor((int)u.y, m);
    return __builtin_bit_cast(half4, u);
}

// ---------------- prep: W_conv (l=0..3) + W_enc (l=4) -> fp16 B-fragment layout ----------------
__global__ __launch_bounds__(256) void k_prepW(const float* __restrict__ Wconv,
                                               const float* __restrict__ Wenc,
                                               __h* __restrict__ Wh) {
    int idx = blockIdx.x * 256 + threadIdx.x;        // l*4096 + k*64 + n
    int l = idx >> 12;
    int kn = idx & 4095;
    int k = kn >> 6, n = kn & 63;
    int nt = n >> 4, nl = n & 15;
    int kt = k >> 5, kr = k & 31;
    int quad = kr >> 3, j = kr & 7;
    int lane = quad * 16 + nl;
    int pos = (((nt * 2 + kt) * 64 + lane) << 3) + j;
    float w = (l < N_LAYERS) ? Wconv[(size_t)l * 4096 + kn] : Wenc[kn];
    Wh[(l << 12) + pos] = (__h)w;
}

// ---------------- fused layer: gather + MFMA GEMM ----------------
// Two waves cooperate per 16-row tile (8 rows gathered per wave -> 2x wave count
// vs 16 rows/wave, for latency hiding). The tile's csr_src segment is contiguous
// (rows are consecutive nodes) and is pre-staged coalesced into LDS, removing the
// index load from the gather's dependent chain. Both waves redundantly run the
// 16x64 @ 64x64 MFMA (MfmaUtil ~0.5%, redundancy free); epilogue split by quad.
// last=0: Gho = fp16( dis * silu(v + b) );  last=1: pooled[batch] += silu(v + b)
__global__ __launch_bounds__(256) void k_layer(const int* __restrict__ csr_src,
                                               const int* __restrict__ rowptr,
                                               const float* __restrict__ dis,
                                               const __h* __restrict__ G,
                                               const __h* __restrict__ Wh,
                                               const float* __restrict__ bias,
                                               const int* __restrict__ batch,
                                               __h* __restrict__ Gho,
                                               float* __restrict__ pooled,
                                               int N, int last) {
    __shared__ __attribute__((aligned(16))) __h At[2][16][72];  // 72-pad: cheap A-frag reads
    __shared__ int sidx[2][IDX_CAP];
    int tid  = threadIdx.x;
    int wave = tid >> 6;
    int lane = tid & 63;
    int tile = wave >> 1;        // 0..1: which 16-row tile of this block
    int half = wave & 1;         // 0..1: which 8 rows of the tile this wave gathers
    int trow0 = blockIdx.x * 32 + tile * 16;
    int grp = lane >> 4;         // 0..3 edge groups (also MFMA quad)
    int f4  = lane & 15;         // 8-byte chunk of the 128-B row (also MFMA nl)

    // rowptr[trow0 .. trow0+16] via lanes + shfl broadcast
    int rpi = trow0 + lane;
    int rpv = rowptr[rpi > N ? N : rpi];
    int beg0 = __shfl(rpv, 0);
    int endL = __shfl(rpv, 16);
    int Lc   = endL - beg0; if (Lc > IDX_CAP) Lc = IDX_CAP;

    // stage the tile's contiguous csr segment, coalesced across the wave pair
    int t2 = tid & 127;
    const int* __restrict__ gsrc = csr_src + beg0;
    for (int k = t2; k < Lc; k += 128) sidx[tile][k] = gsrc[k];
    __syncthreads();

    const half4 z = {(__h)0.f, (__h)0.f, (__h)0.f, (__h)0.f};
    const int* sp = sidx[tile];
    #pragma unroll 2
    for (int r = 0; r < 8; ++r) {
        int i = half * 8 + r;
        int beg = __shfl(rpv, i);
        int end = __shfl(rpv, i + 1);
        half4 a = z;
        int e = beg + grp;
        while (e < end) {
            int o = e - beg0;
            int s0 =                  (o      < IDX_CAP) ? sp[o]      : csr_src[e];
            int s1 = (e + 4  < end) ? ((o + 4  < IDX_CAP) ? sp[o + 4]  : csr_src[e + 4])  : -1;
            int s2 = (e + 8  < end) ? ((o + 8  < IDX_CAP) ? sp[o + 8]  : csr_src[e + 8])  : -1;
            int s3 = (e + 12 < end) ? ((o + 12 < IDX_CAP) ? sp[o + 12] : csr_src[e + 12]) : -1;
            int s4 = (e + 16 < end) ? ((o + 16 < IDX_CAP) ? sp[o + 16] : csr_src[e + 16]) : -1;
            int s5 = (e + 20 < end) ? ((o + 20 < IDX_CAP) ? sp[o + 20] : csr_src[e + 20]) : -1;
            int s6 = (e + 24 < end) ? ((o + 24 < IDX_CAP) ? sp[o + 24] : csr_src[e + 24]) : -1;
            int s7 = (e + 28 < end) ? ((o + 28 < IDX_CAP) ? sp[o + 28] : csr_src[e + 28]) : -1;
            half4 r0 = ((const half4*)(G + (size_t)s0 * 64))[f4];
            half4 r1 = (s1 >= 0) ? ((const half4*)(G + (size_t)s1 * 64))[f4] : z;
            half4 r2 = (s2 >= 0) ? ((const half4*)(G + (size_t)s2 * 64))[f4] : z;
            half4 r3 = (s3 >= 0) ? ((const half4*)(G + (size_t)s3 * 64))[f4] : z;
            half4 r4 = (s4 >= 0) ? ((const half4*)(G + (size_t)s4 * 64))[f4] : z;
            half4 r5 = (s5 >= 0) ? ((const half4*)(G + (size_t)s5 * 64))[f4] : z;
            half4 r6 = (s6 >= 0) ? ((const half4*)(G + (size_t)s6 * 64))[f4] : z;
            half4 r7 = (s7 >= 0) ? ((const half4*)(G + (size_t)s7 * 64))[f4] : z;
            a += r0; a += r1; a += r2; a += r3;
            a += r4; a += r5; a += r6; a += r7;
            e += 32;
        }
        a += shfl_xor_h4(a, 16);
        a += shfl_xor_h4(a, 32);
        if (grp == 0) {
            int node = trow0 + i;
            float df = (node < N) ? dis[node] : 0.0f;
            __h dd = (__h)df;
            ((half4*)&At[tile][i][0])[f4] = a * dd;
        }
    }
    __syncthreads();

    int quad = grp, nl = f4;
    half8 bf[4][2];
    #pragma unroll
    for (int nt = 0; nt < 4; ++nt)
        #pragma unroll
        for (int kt = 0; kt < 2; ++kt)
            bf[nt][kt] = *(const half8*)(Wh + (((nt * 2 + kt) * 64 + lane) << 3));

    half8 a0 = *(const half8*)&At[tile][nl][quad * 8];
    half8 a1 = *(const half8*)&At[tile][nl][32 + quad * 8];

    f32x4 acc[4];
    #pragma unroll
    for (int nt = 0; nt < 4; ++nt) {
        acc[nt] = (f32x4){0.f, 0.f, 0.f, 0.f};
        acc[nt] = __builtin_amdgcn_mfma_f32_16x16x32_f16(a0, bf[nt][0], acc[nt], 0, 0, 0);
        acc[nt] = __builtin_amdgcn_mfma_f32_16x16x32_f16(a1, bf[nt][1], acc[nt], 0, 0, 0);
    }

    float b[4];
    #pragma unroll
    for (int nt = 0; nt < 4; ++nt) b[nt] = bias[nt * 16 + nl];

    // epilogue ownership: quads 0-1 cover rows 0-7 (wave half 0), quads 2-3 rows 8-15
    bool own = ((quad >> 1) == half);

    if (!last) {
        if (own) {
            #pragma unroll
            for (int reg = 0; reg < 4; ++reg) {
                int rr = trow0 + quad * 4 + reg;
                if (rr < N) {
                    float ds_ = dis[rr];
                    #pragma unroll
                    for (int nt = 0; nt < 4; ++nt) {
                        float v = acc[nt][reg] + b[nt];
                        v = v / (1.0f + expf(-v));
                        Gho[(size_t)rr * 64 + nt * 16 + nl] = (__h)(ds_ * v);
                    }
                }
            }
        }
    } else {
        if (own) {
            float run[4] = {0.f, 0.f, 0.f, 0.f};
            int cur = -1;
            #pragma unroll
            for (int reg = 0; reg < 4; ++reg) {
                int rr = trow0 + quad * 4 + reg;
                if (rr < N) {
                    int bi = batch[rr];
                    float vals[4];
                    #pragma unroll
                    for (int nt = 0; nt < 4; ++nt) {
                        float v = acc[nt][reg] + b[nt];
                        vals[nt] = v / (1.0f + expf(-v));
                    }
                    if (bi != cur) {
                        if (cur >= 0) {
                            #pragma unroll
                            for (int nt = 0; nt < 4; ++nt)
                                atomicAdd(&pooled[cur * 64 + nt * 16 + nl], run[nt]);
                        }
                        cur = bi;
                        #pragma unroll
                        for (int nt = 0; nt < 4; ++nt) run[nt] = vals[nt];
                    } else {
                        #pragma unroll
                        for (int nt = 0; nt < 4; ++nt) run[nt] += vals[nt];
                    }
                }
            }
            if (cur >= 0) {
                #pragma unroll
                for (int nt = 0; nt < 4; ++nt)
                    atomicAdd(&pooled[cur * 64 + nt * 16 + nl], run[nt]);
            }
        }
    }
}

// ---------------- MFMA GEMM (encoder only): [N,64]fp32 @ [64,64]fp16, 32 rows/wave ----------------
__global__ __launch_bounds__(256) void k_gemm_mfma(const float* __restrict__ xf,
                                                   const __h* __restrict__ Wh,
                                                   const float* __restrict__ bias,
                                                   const float* __restrict__ dis,
                                                   __h* __restrict__ Gho,
                                                   int N) {
    int wave = threadIdx.x >> 6;
    int lane = threadIdx.x & 63;
    int row0 = (blockIdx.x * 4 + wave) * 32;
    if (row0 >= N) return;
    int quad = lane >> 4, nl = lane & 15;

    half8 bf[4][2];
    #pragma unroll
    for (int nt = 0; nt < 4; ++nt)
        #pragma unroll
        for (int kt = 0; kt < 2; ++kt)
            bf[nt][kt] = *(const half8*)(Wh + (((nt * 2 + kt) * 64 + lane) << 3));

    f32x4 acc[2][4];
    #pragma unroll
    for (int h = 0; h < 2; ++h) {
        int r = row0 + h * 16 + nl; if (r >= N) r = N - 1;
        const float* ap = xf + (size_t)r * 64 + quad * 8;
        float4 v0 = ((const float4*)ap)[0];
        float4 v1 = ((const float4*)ap)[1];
        float4 v2 = ((const float4*)(ap + 32))[0];
        float4 v3 = ((const float4*)(ap + 32))[1];
        half8 a0 = (half8){(__h)v0.x, (__h)v0.y, (__h)v0.z, (__h)v0.w,
                           (__h)v1.x, (__h)v1.y, (__h)v1.z, (__h)v1.w};
        half8 a1 = (half8){(__h)v2.x, (__h)v2.y, (__h)v2.z, (__h)v2.w,
                           (__h)v3.x, (__h)v3.y, (__h)v3.z, (__h)v3.w};
        #pragma unroll
        for (int nt = 0; nt < 4; ++nt) {
            acc[h][nt] = (f32x4){0.f, 0.f, 0.f, 0.f};
            acc[h][nt] = __builtin_amdgcn_mfma_f32_16x16x32_f16(a0, bf[nt][0], acc[h][nt], 0, 0, 0);
            acc[h][nt] = __builtin_amdgcn_mfma_f32_16x16x32_f16(a1, bf[nt][1], acc[h][nt], 0, 0, 0);
        }
    }

    float b[4];
    #pragma unroll
    for (int nt = 0; nt < 4; ++nt) b[nt] = bias[nt * 16 + nl];

    #pragma unroll
    for (int h = 0; h < 2; ++h) {
        #pragma unroll
        for (int reg = 0; reg < 4; ++reg) {
            int rr = row0 + h * 16 + quad * 4 + reg;
            if (rr < N) {
                float ds = dis[rr];
                #pragma unroll
                for (int nt = 0; nt < 4; ++nt) {
                    float v = acc[h][nt][reg] + b[nt];
                    Gho[(size_t)rr * 64 + nt * 16 + nl] = (__h)(ds * v);
                }
            }
        }
    }
}

// ---------------- readout ----------------
__global__ __launch_bounds__(256) void k_readout(const float* __restrict__ pooled,
                                                 const float* __restrict__ Wout,
                                                 const float* __restrict__ bout,
                                                 float* __restrict__ out) {
    int idx = blockIdx.x * 256 + threadIdx.x;
    if (idx >= N_GRAPHS * N_CLASSES) return;
    int g = idx / N_CLASSES, c = idx % N_CLASSES;
    float s = bout[c];
    #pragma unroll
    for (int j = 0; j < 64; ++j) s += pooled[g * 64 + j] * Wout[j * N_CLASSES + c];
    out[idx] = fmaxf(s, 0.0f);
}

extern "C" void kernel_launch(void* const* d_in, const int* in_sizes, int n_in,
                              void* d_out, int out_size, void* d_ws, size_t ws_size,
                              hipStream_t stream) {
    const float* x      = (const float*)d_in[0];
    const int*   ei     = (const int*)d_in[1];
    const int*   batch  = (const int*)d_in[2];
    const float* W_enc  = (const float*)d_in[3];
    const float* b_enc  = (const float*)d_in[4];
    const float* W_conv = (const float*)d_in[5];
    const float* b_conv = (const float*)d_in[6];
    const float* W_out  = (const float*)d_in[7];
    const float* b_out  = (const float*)d_in[8];
    float* out = (float*)d_out;

    const int N = in_sizes[2];
    const int E = in_sizes[1] / 2;
    const int* src = ei;
    const int* dst = ei + E;
    const int NB   = (N + NPB - 1) >> BSH;
    const int NBLK = (E + PART_K - 1) / PART_K;

    char* ws = (char*)d_ws;
    size_t off = 0;
    auto alloc = [&](size_t bytes) -> char* {
        char* p = ws + off;
        off += (bytes + 255) & ~(size_t)255;
        return p;
    };
    int*   ghist      = (int*)alloc((size_t)(NB + 1) * sizeof(int));
    int*   bucketbase = (int*)alloc((size_t)(NB + 1) * sizeof(int));
    int*   gcur       = (int*)alloc((size_t)(NB + 1) * sizeof(int));
    int*   packed     = (int*)alloc((size_t)E * sizeof(int));
    int*   csr_src    = (int*)alloc((size_t)(E + N) * sizeof(int));
    int*   rowptr     = (int*)alloc((size_t)(N + 1) * sizeof(int));
    float* dis        = (float*)alloc((size_t)N * sizeof(float));
    __h*   bufA       = (__h*)alloc((size_t)N * HIDDEN * sizeof(__h));
    __h*   bufB       = (__h*)alloc((size_t)N * HIDDEN * sizeof(__h));
    __h*   Wh         = (__h*)alloc((size_t)(N_LAYERS + 1) * 4096 * sizeof(__h));
    float* pooled     = (float*)alloc((size_t)N_GRAPHS * HIDDEN * sizeof(float));
    (void)ws_size;

    hipMemsetAsync(ghist, 0, (size_t)(NB + 1) * sizeof(int), stream);
    hipMemsetAsync(pooled, 0, (size_t)N_GRAPHS * HIDDEN * sizeof(float), stream);

    k_histA     <<<NBLK, 256, 0, stream>>>(dst, ghist, E, NB);
    k_bucketscan<<<1,    256, 0, stream>>>(ghist, bucketbase, gcur, NB);
    k_partition <<<NBLK, 256, 0, stream>>>(src, dst, gcur, packed, E, NB);
    k_fill3     <<<NB,   256, 0, stream>>>(packed, bucketbase, rowptr, dis, csr_src, N, E);
    k_prepW<<<((N_LAYERS + 1) * 4096) / 256, 256, 0, stream>>>(W_conv, W_enc, Wh);

    // encoder: bufA = fp16(dis * (x @ W_enc + b_enc)) — reads fp32 x directly
    int gb32 = (N + 127) / 128;   // 32 rows/wave, 4 waves/block
    k_gemm_mfma<<<gb32, 256, 0, stream>>>(x, Wh + (size_t)N_LAYERS * 4096, b_enc,
                                          dis, bufA, N);

    // fused conv layers: ping-pong G buffers (fused kernel writes next-layer rows
    // while other blocks still read current-layer rows -> cannot be in-place)
    __h* bufs[2] = {bufA, bufB};
    int glayer = (N + 31) / 32;   // 32 rows/block: 2 tiles x (2 waves x 8 rows)
    for (int l = 0; l < N_LAYERS; ++l) {
        int last = (l == N_LAYERS - 1);
        k_layer<<<glayer, 256, 0, stream>>>(csr_src, rowptr, dis, bufs[l & 1],
                                            Wh + (size_t)l * 4096,
                                            b_conv + (size_t)l * HIDDEN, batch,
                                            bufs[(l + 1) & 1], pooled, N, last);
    }

    k_readout<<<(N_GRAPHS * N_CLASSES + 255) / 256, 256, 0, stream>>>(pooled, W_out, b_out, out);
}

// Round 3
// 319.037 us; speedup vs baseline: 1.0941x; 1.0941x over previous
//
#include <hip/hip_runtime.h>
#include <math.h>

#define HIDDEN 64
#define N_LAYERS 4
#define N_CLASSES 10
#define N_GRAPHS 512
#define BSH 8                        // coarse bucket: 256 nodes
#define NPB 256                      // nodes per bucket
#define PART_K 2048                  // edges per partition block
#define IDX_CAP 512                  // staged csr indices per 16-row tile

typedef _Float16 __h;
typedef __attribute__((ext_vector_type(4))) _Float16 half4;   // 8 B
typedef __attribute__((ext_vector_type(8))) _Float16 half8;   // 16 B, MFMA A/B frag
typedef __attribute__((ext_vector_type(4))) float f32x4;      // MFMA acc

// ---------------- pass 1: global bucket histogram ----------------
__global__ __launch_bounds__(256) void k_histA(const int* __restrict__ dst,
                                               int* __restrict__ ghist, int E, int NB) {
    __shared__ int hist[512];
    int t = threadIdx.x;
    hist[t] = 0; hist[t + 256] = 0;
    __syncthreads();
    int base = blockIdx.x * PART_K;
    int kend = min(PART_K, E - base);
    for (int k = t; k < kend; k += 256) atomicAdd(&hist[dst[base + k] >> BSH], 1);
    __syncthreads();
    for (int j = t; j < NB; j += 256) {
        int h = hist[j];
        if (h) atomicAdd(&ghist[j], h);
    }
}

// ---------------- pass 2: scan bucket sizes -> bases, init cursors ----------------
__global__ __launch_bounds__(256) void k_bucketscan(const int* __restrict__ ghist,
                                                    int* __restrict__ bucketbase,
                                                    int* __restrict__ gcur, int NB) {
    __shared__ int s[256];
    int t = threadIdx.x;
    int j0 = 2 * t, j1 = 2 * t + 1;
    int h0 = (j0 < NB) ? ghist[j0] : 0;
    int h1 = (j1 < NB) ? ghist[j1] : 0;
    s[t] = h0 + h1; __syncthreads();
    for (int o = 1; o < 256; o <<= 1) {
        int x = (t >= o) ? s[t - o] : 0;
        __syncthreads();
        s[t] += x;
        __syncthreads();
    }
    int base = (t == 0) ? 0 : s[t - 1];
    if (j0 <= NB) { bucketbase[j0] = base;      gcur[j0] = base; }
    if (j1 <= NB) { bucketbase[j1] = base + h0; gcur[j1] = base + h0; }
}

// ---------------- pass 3: partition edges into bucket segments (LDS reorder) ----------------
__global__ __launch_bounds__(256) void k_partition(const int* __restrict__ src,
                                                   const int* __restrict__ dst,
                                                   int* __restrict__ gcur,
                                                   int* __restrict__ packed,
                                                   int E, int NB) {
    __shared__ int hist[512];
    __shared__ int scanE[512];
    __shared__ int cur[512];
    __shared__ int delta[512];
    __shared__ int ps[256];
    __shared__ int stage[PART_K];
    __shared__ unsigned short stgj[PART_K];
    int t = threadIdx.x;
    int base = blockIdx.x * PART_K;
    int kend = min(PART_K, E - base);

    hist[t] = 0; hist[t + 256] = 0;
    __syncthreads();
    for (int k = t; k < kend; k += 256) atomicAdd(&hist[dst[base + k] >> BSH], 1);
    __syncthreads();

    int j0 = 2 * t, j1 = j0 + 1;
    int h0 = hist[j0], h1 = hist[j1];
    ps[t] = h0 + h1; __syncthreads();
    for (int o = 1; o < 256; o <<= 1) {
        int x = (t >= o) ? ps[t - o] : 0;
        __syncthreads();
        ps[t] += x;
        __syncthreads();
    }
    int bexc = (t == 0) ? 0 : ps[t - 1];
    scanE[j0] = bexc;
    scanE[j1] = bexc + h0;
    __syncthreads();

    for (int j = t; j < NB; j += 256) {
        int h = hist[j];
        int g = h ? atomicAdd(&gcur[j], h) : 0;
        delta[j] = g - scanE[j];
        cur[j]   = scanE[j];
    }
    __syncthreads();

    for (int k = t; k < kend; k += 256) {
        int d = dst[base + k], s = src[base + k];
        int j = d >> BSH;
        int pos = atomicAdd(&cur[j], 1);
        stage[pos] = (s << BSH) | (d & (NPB - 1));
        stgj[pos]  = (unsigned short)j;
    }
    __syncthreads();

    for (int i = t; i < kend; i += 256) {
        packed[i + delta[stgj[i]]] = stage[i];
    }
}

// ---------------- pass 4: per-bucket CSR fill with SELF-EDGE prepend ----------------
__global__ __launch_bounds__(256) void k_fill3(const int* __restrict__ packed,
                                               const int* __restrict__ bucketbase,
                                               int* __restrict__ rowptr,
                                               float* __restrict__ dis,
                                               int* __restrict__ csr_src,
                                               int N, int E) {
    __shared__ int cnt[256];
    __shared__ int rp[256];
    int j = blockIdx.x;
    int t = threadIdx.x;
    int node0 = j << BSH;
    int segb = bucketbase[j];       // packed (real-edge) base
    int sege = bucketbase[j + 1];

    cnt[t] = 0; __syncthreads();
    for (int i = segb + t; i < sege; i += 256) atomicAdd(&cnt[packed[i] & (NPB - 1)], 1);
    __syncthreads();

    int c = cnt[t];
    rp[t] = c; __syncthreads();
    for (int o = 1; o < 256; o <<= 1) {
        int x = (t >= o) ? rp[t - o] : 0;
        __syncthreads();
        rp[t] += x;
        __syncthreads();
    }
    int node = node0 + t;
    int start = segb + rp[t] - c + node;   // + node = selves before this node
    if (node < N) {
        rowptr[node] = start;
        dis[node] = rsqrtf((float)c + 1.0f);
        csr_src[start] = node;             // self edge first
        if (node == N - 1) rowptr[N] = E + N;
    }
    __syncthreads();
    cnt[t] = start + 1;                    // cursor after the self slot
    __syncthreads();
    for (int i = segb + t; i < sege; i += 256) {
        int v = packed[i];
        int slot = atomicAdd(&cnt[v & (NPB - 1)], 1);
        csr_src[slot] = v >> BSH;
    }
}

// ---------------- prep: W_conv (l=0..3) + W_enc (l=4) -> fp16 B-fragment layout ----------------
__global__ __launch_bounds__(256) void k_prepW(const float* __restrict__ Wconv,
                                               const float* __restrict__ Wenc,
                                               __h* __restrict__ Wh) {
    int idx = blockIdx.x * 256 + threadIdx.x;        // l*4096 + k*64 + n
    int l = idx >> 12;
    int kn = idx & 4095;
    int k = kn >> 6, n = kn & 63;
    int nt = n >> 4, nl = n & 15;
    int kt = k >> 5, kr = k & 31;
    int quad = kr >> 3, j = kr & 7;
    int lane = quad * 16 + nl;
    int pos = (((nt * 2 + kt) * 64 + lane) << 3) + j;
    float w = (l < N_LAYERS) ? Wconv[(size_t)l * 4096 + kn] : Wenc[kn];
    Wh[(l << 12) + pos] = (__h)w;
}

// ---------------- fused layer: gather + MFMA GEMM ----------------
// Gather geometry: 8-lane groups, ONE ROW PER GROUP (16 B/lane). A wave gathers
// its 8 rows in parallel (vs. serially), with no cross-lane reduce at all; two
// waves cooperate per 16-row tile. Tile's contiguous csr segment staged in LDS
// (tile-uniform fits-branch; global fallback essentially never taken).
// Both waves redundantly run the 16x64 @ 64x64 MFMA; epilogue split by quad.
// last=0: Gho = fp16( dis * silu(v + b) );  last=1: pooled[batch] += silu(v + b)
__global__ __launch_bounds__(256) void k_layer(const int* __restrict__ csr_src,
                                               const int* __restrict__ rowptr,
                                               const float* __restrict__ dis,
                                               const __h* __restrict__ G,
                                               const __h* __restrict__ Wh,
                                               const float* __restrict__ bias,
                                               const int* __restrict__ batch,
                                               __h* __restrict__ Gho,
                                               float* __restrict__ pooled,
                                               int N, int last) {
    __shared__ __attribute__((aligned(16))) __h At[2][16][72];  // 144-B row stride, 16B-aligned
    __shared__ int sidx[2][IDX_CAP];
    int tid  = threadIdx.x;
    int wave = tid >> 6;
    int lane = tid & 63;
    int tile = wave >> 1;        // 0..1: which 16-row tile of this block
    int half = wave & 1;         // 0..1: which 8 rows of the tile this wave gathers
    int trow0 = blockIdx.x * 32 + tile * 16;
    int g8  = lane >> 3;         // 0..7: row group (one row per group)
    int f8  = lane & 7;          // 16-B chunk of the 128-B row
    unsigned f8b = (unsigned)f8 * 16u;

    // rowptr[trow0 .. trow0+16] via lanes + shfl broadcast
    int rpi = trow0 + lane;
    int rpv = rowptr[rpi > N ? N : rpi];
    int beg0 = __shfl(rpv, 0);
    int endL = __shfl(rpv, 16);
    int L    = endL - beg0;
    bool fits = (L <= IDX_CAP);

    // stage the tile's contiguous csr segment, coalesced across the wave pair
    if (fits) {
        int t2 = tid & 127;
        const int* __restrict__ gsrc = csr_src + beg0;
        for (int k = t2; k < L; k += 128) sidx[tile][k] = gsrc[k];
    }
    __syncthreads();

    int i   = half * 8 + g8;     // row of the tile this group owns (0..15)
    int beg = __shfl(rpv, i);
    int end = __shfl(rpv, i + 1);
    int node = trow0 + i;

    const char* Gb = (const char*)G;
    const half8 z8 = {(__h)0.f, (__h)0.f, (__h)0.f, (__h)0.f,
                      (__h)0.f, (__h)0.f, (__h)0.f, (__h)0.f};
    half8 a = z8;
#define GLOAD(s) (*(const half8*)(Gb + ((((unsigned)(s)) << 7) + f8b)))

    if (fits) {
        const int* sp = sidx[tile];
        int e = beg - beg0, ee = end - beg0;
        for (; e + 8 <= ee; e += 8) {
            int s0 = sp[e + 0], s1 = sp[e + 1], s2 = sp[e + 2], s3 = sp[e + 3];
            int s4 = sp[e + 4], s5 = sp[e + 5], s6 = sp[e + 6], s7 = sp[e + 7];
            half8 r0 = GLOAD(s0), r1 = GLOAD(s1), r2 = GLOAD(s2), r3 = GLOAD(s3);
            half8 r4 = GLOAD(s4), r5 = GLOAD(s5), r6 = GLOAD(s6), r7 = GLOAD(s7);
            a += r0; a += r1; a += r2; a += r3;
            a += r4; a += r5; a += r6; a += r7;
        }
        if (e < ee) {
            #pragma unroll
            for (int k = 0; k < 8; ++k) {
                int ek = e + k;
                int ck = ek < ee ? ek : ee - 1;
                half8 r = GLOAD(sp[ck]);
                a += (ek < ee) ? r : z8;
            }
        }
    } else {
        int e = beg, ee = end;
        for (; e + 8 <= ee; e += 8) {
            int s0 = csr_src[e + 0], s1 = csr_src[e + 1], s2 = csr_src[e + 2], s3 = csr_src[e + 3];
            int s4 = csr_src[e + 4], s5 = csr_src[e + 5], s6 = csr_src[e + 6], s7 = csr_src[e + 7];
            half8 r0 = GLOAD(s0), r1 = GLOAD(s1), r2 = GLOAD(s2), r3 = GLOAD(s3);
            half8 r4 = GLOAD(s4), r5 = GLOAD(s5), r6 = GLOAD(s6), r7 = GLOAD(s7);
            a += r0; a += r1; a += r2; a += r3;
            a += r4; a += r5; a += r6; a += r7;
        }
        if (e < ee) {
            #pragma unroll
            for (int k = 0; k < 8; ++k) {
                int ek = e + k;
                int ck = ek < ee ? ek : ee - 1;
                half8 r = GLOAD(csr_src[ck]);
                a += (ek < ee) ? r : z8;
            }
        }
    }
#undef GLOAD

    float df = (node < N) ? dis[node] : 0.0f;
    __h dd = (__h)df;
    half8 dv = {dd, dd, dd, dd, dd, dd, dd, dd};
    a = a * dv;
    *(half8*)&At[tile][i][f8 * 8] = a;
    __syncthreads();

    int quad = lane >> 4, nl = lane & 15;
    half8 bf[4][2];
    #pragma unroll
    for (int nt = 0; nt < 4; ++nt)
        #pragma unroll
        for (int kt = 0; kt < 2; ++kt)
            bf[nt][kt] = *(const half8*)(Wh + (((nt * 2 + kt) * 64 + lane) << 3));

    half8 a0 = *(const half8*)&At[tile][nl][quad * 8];
    half8 a1 = *(const half8*)&At[tile][nl][32 + quad * 8];

    f32x4 acc[4];
    #pragma unroll
    for (int nt = 0; nt < 4; ++nt) {
        acc[nt] = (f32x4){0.f, 0.f, 0.f, 0.f};
        acc[nt] = __builtin_amdgcn_mfma_f32_16x16x32_f16(a0, bf[nt][0], acc[nt], 0, 0, 0);
        acc[nt] = __builtin_amdgcn_mfma_f32_16x16x32_f16(a1, bf[nt][1], acc[nt], 0, 0, 0);
    }

    float b[4];
    #pragma unroll
    for (int nt = 0; nt < 4; ++nt) b[nt] = bias[nt * 16 + nl];

    // epilogue ownership: quads 0-1 cover rows 0-7 (wave half 0), quads 2-3 rows 8-15
    bool own = ((quad >> 1) == half);

    if (!last) {
        if (own) {
            #pragma unroll
            for (int reg = 0; reg < 4; ++reg) {
                int rr = trow0 + quad * 4 + reg;
                if (rr < N) {
                    float ds_ = dis[rr];
                    #pragma unroll
                    for (int nt = 0; nt < 4; ++nt) {
                        float v = acc[nt][reg] + b[nt];
                        v = v / (1.0f + expf(-v));
                        Gho[(size_t)rr * 64 + nt * 16 + nl] = (__h)(ds_ * v);
                    }
                }
            }
        }
    } else {
        if (own) {
            float run[4] = {0.f, 0.f, 0.f, 0.f};
            int cur = -1;
            #pragma unroll
            for (int reg = 0; reg < 4; ++reg) {
                int rr = trow0 + quad * 4 + reg;
                if (rr < N) {
                    int bi = batch[rr];
                    float vals[4];
                    #pragma unroll
                    for (int nt = 0; nt < 4; ++nt) {
                        float v = acc[nt][reg] + b[nt];
                        vals[nt] = v / (1.0f + expf(-v));
                    }
                    if (bi != cur) {
                        if (cur >= 0) {
                            #pragma unroll
                            for (int nt = 0; nt < 4; ++nt)
                                atomicAdd(&pooled[cur * 64 + nt * 16 + nl], run[nt]);
                        }
                        cur = bi;
                        #pragma unroll
                        for (int nt = 0; nt < 4; ++nt) run[nt] = vals[nt];
                    } else {
                        #pragma unroll
                        for (int nt = 0; nt < 4; ++nt) run[nt] += vals[nt];
                    }
                }
            }
            if (cur >= 0) {
                #pragma unroll
                for (int nt = 0; nt < 4; ++nt)
                    atomicAdd(&pooled[cur * 64 + nt * 16 + nl], run[nt]);
            }
        }
    }
}

// ---------------- MFMA GEMM (encoder only): [N,64]fp32 @ [64,64]fp16, 32 rows/wave ----------------
__global__ __launch_bounds__(256) void k_gemm_mfma(const float* __restrict__ xf,
                                                   const __h* __restrict__ Wh,
                                                   const float* __restrict__ bias,
                                                   const float* __restrict__ dis,
                                                   __h* __restrict__ Gho,
                                                   int N) {
    int wave = threadIdx.x >> 6;
    int lane = threadIdx.x & 63;
    int row0 = (blockIdx.x * 4 + wave) * 32;
    if (row0 >= N) return;
    int quad = lane >> 4, nl = lane & 15;

    half8 bf[4][2];
    #pragma unroll
    for (int nt = 0; nt < 4; ++nt)
        #pragma unroll
        for (int kt = 0; kt < 2; ++kt)
            bf[nt][kt] = *(const half8*)(Wh + (((nt * 2 + kt) * 64 + lane) << 3));

    f32x4 acc[2][4];
    #pragma unroll
    for (int h = 0; h < 2; ++h) {
        int r = row0 + h * 16 + nl; if (r >= N) r = N - 1;
        const float* ap = xf + (size_t)r * 64 + quad * 8;
        float4 v0 = ((const float4*)ap)[0];
        float4 v1 = ((const float4*)ap)[1];
        float4 v2 = ((const float4*)(ap + 32))[0];
        float4 v3 = ((const float4*)(ap + 32))[1];
        half8 a0 = (half8){(__h)v0.x, (__h)v0.y, (__h)v0.z, (__h)v0.w,
                           (__h)v1.x, (__h)v1.y, (__h)v1.z, (__h)v1.w};
        half8 a1 = (half8){(__h)v2.x, (__h)v2.y, (__h)v2.z, (__h)v2.w,
                           (__h)v3.x, (__h)v3.y, (__h)v3.z, (__h)v3.w};
        #pragma unroll
        for (int nt = 0; nt < 4; ++nt) {
            acc[h][nt] = (f32x4){0.f, 0.f, 0.f, 0.f};
            acc[h][nt] = __builtin_amdgcn_mfma_f32_16x16x32_f16(a0, bf[nt][0], acc[h][nt], 0, 0, 0);
            acc[h][nt] = __builtin_amdgcn_mfma_f32_16x16x32_f16(a1, bf[nt][1], acc[h][nt], 0, 0, 0);
        }
    }

    float b[4];
    #pragma unroll
    for (int nt = 0; nt < 4; ++nt) b[nt] = bias[nt * 16 + nl];

    #pragma unroll
    for (int h = 0; h < 2; ++h) {
        #pragma unroll
        for (int reg = 0; reg < 4; ++reg) {
            int rr = row0 + h * 16 + quad * 4 + reg;
            if (rr < N) {
                float ds = dis[rr];
                #pragma unroll
                for (int nt = 0; nt < 4; ++nt) {
                    float v = acc[h][nt][reg] + b[nt];
                    Gho[(size_t)rr * 64 + nt * 16 + nl] = (__h)(ds * v);
                }
            }
        }
    }
}

// ---------------- readout ----------------
__global__ __launch_bounds__(256) void k_readout(const float* __restrict__ pooled,
                                                 const float* __restrict__ Wout,
                                                 const float* __restrict__ bout,
                                                 float* __restrict__ out) {
    int idx = blockIdx.x * 256 + threadIdx.x;
    if (idx >= N_GRAPHS * N_CLASSES) return;
    int g = idx / N_CLASSES, c = idx % N_CLASSES;
    float s = bout[c];
    #pragma unroll
    for (int j = 0; j < 64; ++j) s += pooled[g * 64 + j] * Wout[j * N_CLASSES + c];
    out[idx] = fmaxf(s, 0.0f);
}

extern "C" void kernel_launch(void* const* d_in, const int* in_sizes, int n_in,
                              void* d_out, int out_size, void* d_ws, size_t ws_size,
                              hipStream_t stream) {
    const float* x      = (const float*)d_in[0];
    const int*   ei     = (const int*)d_in[1];
    const int*   batch  = (const int*)d_in[2];
    const float* W_enc  = (const float*)d_in[3];
    const float* b_enc  = (const float*)d_in[4];
    const float* W_conv = (const float*)d_in[5];
    const float* b_conv = (const float*)d_in[6];
    const float* W_out  = (const float*)d_in[7];
    const float* b_out  = (const float*)d_in[8];
    float* out = (float*)d_out;

    const int N = in_sizes[2];
    const int E = in_sizes[1] / 2;
    const int* src = ei;
    const int* dst = ei + E;
    const int NB   = (N + NPB - 1) >> BSH;
    const int NBLK = (E + PART_K - 1) / PART_K;

    char* ws = (char*)d_ws;
    size_t off = 0;
    auto alloc = [&](size_t bytes) -> char* {
        char* p = ws + off;
        off += (bytes + 255) & ~(size_t)255;
        return p;
    };
    int*   ghist      = (int*)alloc((size_t)(NB + 1) * sizeof(int));
    int*   bucketbase = (int*)alloc((size_t)(NB + 1) * sizeof(int));
    int*   gcur       = (int*)alloc((size_t)(NB + 1) * sizeof(int));
    int*   packed     = (int*)alloc((size_t)E * sizeof(int));
    int*   csr_src    = (int*)alloc((size_t)(E + N) * sizeof(int));
    int*   rowptr     = (int*)alloc((size_t)(N + 1) * sizeof(int));
    float* dis        = (float*)alloc((size_t)N * sizeof(float));
    __h*   bufA       = (__h*)alloc((size_t)N * HIDDEN * sizeof(__h));
    __h*   bufB       = (__h*)alloc((size_t)N * HIDDEN * sizeof(__h));
    __h*   Wh         = (__h*)alloc((size_t)(N_LAYERS + 1) * 4096 * sizeof(__h));
    float* pooled     = (float*)alloc((size_t)N_GRAPHS * HIDDEN * sizeof(float));
    (void)ws_size;

    hipMemsetAsync(ghist, 0, (size_t)(NB + 1) * sizeof(int), stream);
    hipMemsetAsync(pooled, 0, (size_t)N_GRAPHS * HIDDEN * sizeof(float), stream);

    k_histA     <<<NBLK, 256, 0, stream>>>(dst, ghist, E, NB);
    k_bucketscan<<<1,    256, 0, stream>>>(ghist, bucketbase, gcur, NB);
    k_partition <<<NBLK, 256, 0, stream>>>(src, dst, gcur, packed, E, NB);
    k_fill3     <<<NB,   256, 0, stream>>>(packed, bucketbase, rowptr, dis, csr_src, N, E);
    k_prepW<<<((N_LAYERS + 1) * 4096) / 256, 256, 0, stream>>>(W_conv, W_enc, Wh);

    // encoder: bufA = fp16(dis * (x @ W_enc + b_enc)) — reads fp32 x directly
    int gb32 = (N + 127) / 128;   // 32 rows/wave, 4 waves/block
    k_gemm_mfma<<<gb32, 256, 0, stream>>>(x, Wh + (size_t)N_LAYERS * 4096, b_enc,
                                          dis, bufA, N);

    // fused conv layers: ping-pong G buffers
    __h* bufs[2] = {bufA, bufB};
    int glayer = (N + 31) / 32;   // 32 rows/block: 2 tiles x (2 waves x 8 rows)
    for (int l = 0; l < N_LAYERS; ++l) {
        int last = (l == N_LAYERS - 1);
        k_layer<<<glayer, 256, 0, stream>>>(csr_src, rowptr, dis, bufs[l & 1],
                                            Wh + (size_t)l * 4096,
                                            b_conv + (size_t)l * HIDDEN, batch,
                                            bufs[(l + 1) & 1], pooled, N, last);
    }

    k_readout<<<(N_GRAPHS * N_CLASSES + 255) / 256, 256, 0, stream>>>(pooled, W_out, b_out, out);
}